// Round 10
// baseline (361.311 us; speedup 1.0000x reference)
//
#include <hip/hip_runtime.h>
#include <hip/hip_bf16.h>

using bf16 = __hip_bfloat16;
typedef __attribute__((ext_vector_type(8))) short bf16x8;
typedef __attribute__((ext_vector_type(4))) float f32x4;

#define BB   8
#define NN   12288
#define NTOK (BB*NN)      // 98304
#define NTK  3072
#define CC   256
#define CCO  512
#define HH   128
#define WWI  96
#define HWIN (HH*WWI)     // 12288
#define H2   64
#define W2   48
#define HW2  (H2*W2)      // 3072
#define RR   (BB*NTK)     // 24576

// ---- workspace layout (float-word offsets)
#define O_CONV  0LL          // conv bf16: 6291456 elems -> 3145728 words
#define O_XD    6291456LL    // xdf bf16 fragment layout: 3145728 words
#define O_AUX   9437184LL    // (unused, layout stability)
#define O_ST2P  9437440LL    // 8192 words: 8 partials x (512 sum | 512 sumsq)
#define O_WT    12582912LL   // wTf bf16 fragment layout: 65536 words
#define O_TK    12713984LL   // tickets: [0]=unused, [1]=st1
#define O_AB1   12715520LL   // 512
#define O_B2    12716032LL   // 512
#define O_AB2   12716544LL   // 1024 (unused now)
#define O_FLAG  12717568LL   // 4
#define O_S1P   12717572LL   // st1 partials: 192 blocks x 512 = 98304 words
#define O_OFF   12914180LL   // 122880 ints: joint [cells(98304) | targets(24576)]
#define O_LIST  13037060LL   // 196608 ints: listA (cells)
#define O_L4    13233668LL   // 786432 words: int4 per joint-list slot (targets)
#define O_RAW   14020100LL   // 122880 ints: raw histogram (pre-scan)
// end 14142980 words = 56.6 MB (ws ~384 MB)

__device__ __forceinline__ float cvt(float v){ return v; }
__device__ __forceinline__ float cvt(bf16 v){ return __bfloat162float(v); }
template<typename T>
__device__ __forceinline__ float ld(const void* p, long long i){
    return cvt(((const T*)p)[i]);
}
__device__ __forceinline__ float bfu(unsigned short u){
    return __uint_as_float((unsigned)u << 16);
}
__device__ __forceinline__ unsigned short ubf(float f){
    bf16 h = __float2bfloat16(f);
    return *(unsigned short*)&h;
}
template<typename T>
__device__ __forceinline__ f32x4 ld4(const void* p, long long i);
template<>
__device__ __forceinline__ f32x4 ld4<bf16>(const void* p, long long i){
    const ushort4 u = *(const ushort4*)((const unsigned short*)p + i);
    return (f32x4){bfu(u.x), bfu(u.y), bfu(u.z), bfu(u.w)};
}
template<>
__device__ __forceinline__ f32x4 ld4<float>(const void* p, long long i){
    const float4 v = *(const float4*)((const float*)p + i);
    return (f32x4){v.x, v.y, v.z, v.w};
}

#define SCN  (NTOK + RR)     // 122880 = 480*256 = 120*1024
#define SCB  120             // scan tiles of 1024

// K0: init. Zeroes raw[SCN]; block 0 zeroes tickets and computes dtype flag.
__global__ __launch_bounds__(256) void k_init(
        const float* __restrict__ locf, int* __restrict__ raw,
        int* __restrict__ tickets, float* __restrict__ flag){
    const int gid = blockIdx.x*256 + threadIdx.x;
    raw[gid] = 0;
    if (blockIdx.x == 0){
        if (threadIdx.x < 2) tickets[threadIdx.x] = 0;
        if (threadIdx.x == 0){
            int bad = 0;
            for (int i = 0; i < 64; ++i){
                const float v = locf[i];
                if (!(v >= -1.0f && v <= 1.0f)) bad = 1;
            }
            flag[0] = bad ? 1.0f : 0.0f;
        }
    }
}

__device__ __forceinline__ int2 gidx2(float lx, float ly, int h, int w){
    lx = fminf(fmaxf(lx, -1.f), 1.f);
    ly = fminf(fmaxf(ly, -1.f), 1.f);
    int xi = (int)rintf(0.5f*(lx+1.f)*(float)w - 0.5f);
    int yi = (int)rintf(0.5f*(ly+1.f)*(float)h - 0.5f);
    xi = min(max(xi,0), w-1); yi = min(max(yi,0), h-1);
    return make_int2(xi, yi);
}

// K1: joint histogram into raw (cells then targets).
template<typename T>
__device__ void meta_body(const void* loc, const int* __restrict__ iat,
                          int* __restrict__ raw){
    const int tok = blockIdx.x*256 + threadIdx.x;
    const int b = tok / NN;
    const float lx = ld<T>(loc, 2LL*tok);
    const float ly = ld<T>(loc, 2LL*tok + 1);
    const int2 g1 = gidx2(lx, ly, HH, WWI);
    atomicAdd(&raw[b*HWIN + g1.x + g1.y*WWI], 1);
    atomicAdd(&raw[NTOK + b*NTK + iat[tok]], 1);
}
__global__ __launch_bounds__(256) void k_meta(
        const void* loc, const int* __restrict__ iat,
        const float* __restrict__ flag, int* __restrict__ raw){
    if (flag[0] != 0.0f) meta_body<bf16>(loc, iat, raw);
    else                 meta_body<float>(loc, iat, raw);
}

// K2 (R10): SINGLE-kernel exclusive scan, raw -> off. Each block redundantly
// computes its global prefix by parallel-reducing raw[0 .. b*1024) (read-only,
// race-free: raw is never written here), scans its own tile in LDS, writes off.
__global__ __launch_bounds__(1024) void k_scan(
        const int* __restrict__ raw, int* __restrict__ off){
    __shared__ int sm[1024];
    __shared__ int red[1024];
    const int tid = threadIdx.x;
    const int b = blockIdx.x;
    int part = 0;
    const int lim = b*1024;
    for (int i = tid; i < lim; i += 1024) part += raw[i];
    red[tid] = part;
    __syncthreads();
    for (int d = 512; d > 0; d >>= 1){
        if (tid < d) red[tid] += red[tid + d];
        __syncthreads();
    }
    const int prefix = red[0];
    const int gid = b*1024 + tid;
    const int v = raw[gid];
    sm[tid] = v;
    __syncthreads();
    for (int d = 1; d < 1024; d <<= 1){
        const int t = (tid >= d) ? sm[tid-d] : 0;
        __syncthreads();
        sm[tid] += t;
        __syncthreads();
    }
    off[gid] = prefix + sm[tid] - v;           // global exclusive
}

// K3: fill joint CSR. listA[pa] = x-row; list4[pb] = {rx, rc, wv_bits, 0}.
template<typename T>
__device__ void fill_body(const void* loc, const int* __restrict__ ia,
                          const int* __restrict__ iat, const void* wt,
                          int* __restrict__ off, int* __restrict__ list,
                          int4* __restrict__ list4){
    const int tok = blockIdx.x*256 + threadIdx.x;
    const int b = tok / NN;
    const float lx = ld<T>(loc, 2LL*tok);
    const float ly = ld<T>(loc, 2LL*tok + 1);
    const int2 g1 = gidx2(lx, ly, HH, WWI);
    const int2 g2 = gidx2(lx, ly, H2, W2);
    const float wv = ld<T>(wt, tok);
    const int rx = b*NN + ia[tok];
    const int pa = atomicAdd(&off[b*HWIN + g1.x + g1.y*WWI], 1);
    list[pa] = rx;
    const int pb = atomicAdd(&off[NTOK + b*NTK + iat[tok]], 1);
    int4 e; e.x = rx; e.y = b*HW2 + g2.x + g2.y*W2; e.z = __float_as_int(wv); e.w = 0;
    list4[pb] = e;
}
__global__ __launch_bounds__(256) void k_fill(
        const void* loc, const int* __restrict__ ia, const int* __restrict__ iat,
        const void* wt, const float* __restrict__ flag,
        int* __restrict__ off, int* __restrict__ list, int4* __restrict__ list4){
    if (flag[0] != 0.0f) fill_body<bf16>(loc, ia, iat, wt, off, list, list4);
    else                 fill_body<float>(loc, ia, iat, wt, off, list, list4);
}

// K4: gather-conv (R4's measured-best form, unchanged).
template<typename T>
__device__ void conv_body(const void* x, const void* dww,
                          const int* __restrict__ off, const int* __restrict__ list,
                          bf16* __restrict__ conv){
    __shared__ f32x4 red[3][64];
    const int tid = threadIdx.x;
    const int kh = tid >> 6;
    const int lane = tid & 63;
    const int ch0 = lane*4;
    const int cell = blockIdx.x;
    const int b = cell / HW2;
    const int p = cell % HW2;
    const int oh = p / W2, ow = p % W2;
    const int ih = 2*oh - 1 + kh;
    f32x4 part = (f32x4){0.f,0.f,0.f,0.f};
    if (ih >= 0){
        const int gbase = b*HWIN + ih*WWI + 2*ow - 1;
        const int e0 = (gbase >= 0) ? off[gbase] : 0;
        const int e1 = off[gbase+1];
        const int e2 = off[gbase+2];
        const int ms = (ow > 0) ? off[gbase-1] : e0;
        f32x4 w0, w1, w2;
        #pragma unroll
        for (int c = 0; c < 4; ++c){
            w0[c] = ld<T>(dww, (long long)(ch0+c)*9 + kh*3 + 0);
            w1[c] = ld<T>(dww, (long long)(ch0+c)*9 + kh*3 + 1);
            w2[c] = ld<T>(dww, (long long)(ch0+c)*9 + kh*3 + 2);
        }
        f32x4 b0 = (f32x4){0.f,0.f,0.f,0.f};
        f32x4 b1 = (f32x4){0.f,0.f,0.f,0.f};
        f32x4 b2 = (f32x4){0.f,0.f,0.f,0.f};
        int idx = ms;
        while (idx < e2){
            const int cnt = min(e2 - idx, 64);
            const int tokv = (lane < cnt) ? list[idx + lane] : 0;
            int j = 0;
            for (; j + 4 <= cnt; j += 4){
                int oxs[4];
                #pragma unroll
                for (int u = 0; u < 4; ++u)
                    oxs[u] = __shfl(tokv, j+u)*CC + ch0;
                f32x4 xv[4];
                #pragma unroll
                for (int u = 0; u < 4; ++u) xv[u] = ld4<T>(x, (long long)oxs[u]);
                #pragma unroll
                for (int u = 0; u < 4; ++u){
                    const int gi = idx + j + u;
                    if (gi < e0)      b0 += xv[u];
                    else if (gi < e1) b1 += xv[u];
                    else              b2 += xv[u];
                }
            }
            for (; j < cnt; ++j){
                const f32x4 xv = ld4<T>(x, (long long)(__shfl(tokv, j)*CC + ch0));
                const int gi = idx + j;
                if (gi < e0)      b0 += xv;
                else if (gi < e1) b1 += xv;
                else              b2 += xv;
            }
            idx += cnt;
        }
        const float r0 = 1.0f/((float)(e0 - ms) + 1e-6f);
        const float r1 = 1.0f/((float)(e1 - e0) + 1e-6f);
        const float r2 = 1.0f/((float)(e2 - e1) + 1e-6f);
        #pragma unroll
        for (int c = 0; c < 4; ++c)
            part[c] = w0[c]*b0[c]*r0 + w1[c]*b1[c]*r1 + w2[c]*b2[c]*r2;
    }
    red[kh][lane] = part;
    __syncthreads();
    if (kh == 0){
        const f32x4 t0 = red[0][lane];
        const f32x4 t1 = red[1][lane];
        const f32x4 t2 = red[2][lane];
        ushort4 o;
        o.x = ubf(t0[0]+t1[0]+t2[0]);
        o.y = ubf(t0[1]+t1[1]+t2[1]);
        o.z = ubf(t0[2]+t1[2]+t2[2]);
        o.w = ubf(t0[3]+t1[3]+t2[3]);
        *(ushort4*)((unsigned short*)conv + (long long)cell*CC + ch0) = o;
    }
}
__global__ __launch_bounds__(192) void k_conv(
        const void* x, const void* dww, const float* __restrict__ flag,
        const int* __restrict__ off, const int* __restrict__ list,
        bf16* __restrict__ conv){
    if (flag[0] != 0.0f) conv_body<bf16>(x, dww, off, list, conv);
    else                 conv_body<float>(x, dww, off, list, conv);
}

// K5: one target per wave; chain off -> list4 -> x/conv; 8-wide static prefetch.
#define PFN 8
template<typename T>
__device__ void num_body(const void* x, const bf16* __restrict__ conv,
                         const void* skw,
                         const int* __restrict__ off, const int4* __restrict__ list4,
                         bf16* __restrict__ xdf){
    const int tid = threadIdx.x;
    const int wave = tid >> 6;
    const int lane = tid & 63;
    const int ch0 = lane*4;
    const f32x4 sk = ld4<T>(skw, ch0);
    const int gt = blockIdx.x*4 + wave;
    const int gj = NTOK + gt;
    int offv = 0;
    if (lane < 2) offv = off[gj - 1 + lane];
    const int s = __shfl(offv, 0);
    const int e = __shfl(offv, 1);
    f32x4 a = (f32x4){0.f,0.f,0.f,0.f};
    float den = 0.f;
    int idx = s;
    while (idx < e){
        int4 t[PFN];
        #pragma unroll
        for (int k = 0; k < PFN; ++k)
            if (idx + k < e) t[k] = list4[idx + k];
        #pragma unroll
        for (int k = 0; k < PFN; ++k){
            if (idx + k < e){
                const float wv = __int_as_float(t[k].z);
                const f32x4 xv = ld4<T>(x, (long long)t[k].x*CC + ch0);
                const f32x4 cv = ld4<bf16>(conv, (long long)t[k].y*CC + ch0);
                #pragma unroll
                for (int c = 0; c < 4; ++c)
                    a[c] += wv*(sk[c]*xv[c] + cv[c]);
                den += wv;
            }
        }
        idx += PFN;
    }
    const float rl = 1.0f/(den + 1e-6f);
    ushort4 o;
    o.x = ubf(a[0]*rl); o.y = ubf(a[1]*rl);
    o.z = ubf(a[2]*rl); o.w = ubf(a[3]*rl);
    const long long bi = (long long)(gt >> 4)*4096 + (long long)(ch0 >> 3)*128
                       + (long long)(gt & 15)*8 + (ch0 & 7);
    *(ushort4*)((unsigned short*)xdf + bi) = o;
}
__global__ __launch_bounds__(256) void k_num(
        const void* x, const bf16* __restrict__ conv, const void* skw,
        const int* __restrict__ off, const int4* __restrict__ list4,
        const float* __restrict__ flag,
        bf16* __restrict__ xdf){
    if (flag[0] != 0.0f) num_body<bf16>(x, conv, skw, off, list4, xdf);
    else                 num_body<float>(x, conv, skw, off, list4, xdf);
}

// K6: BN1 stats from xdf + fused finalize via last-block ticket (R9 parallel
// coalesced finalize, __hip_atomic_load RELAXED/AGENT).
template<typename T>
__device__ void st1_body(const bf16* __restrict__ xdf, float* __restrict__ s1p,
                         int* __restrict__ ticket, const void* g1, const void* b1,
                         float* __restrict__ ab1){
    __shared__ float ss[CC], sq[CC];
    __shared__ int isLast;
    const int tid = threadIdx.x;
    if (tid < CC){ ss[tid] = 0.f; sq[tid] = 0.f; }
    __syncthreads();
    const int tl = tid & 15;
    const int cg = tid >> 4;          // 0..31 channel group
    const int c0 = cg*8;
    float s[8], q[8];
    #pragma unroll
    for (int k = 0; k < 8; ++k){ s[k] = 0.f; q[k] = 0.f; }
    for (int sb = blockIdx.x; sb < RR/16; sb += gridDim.x){
        const long long o = (long long)sb*512 + cg*16 + tl;
        const bf16x8 v = *((const bf16x8*)xdf + o);
        #pragma unroll
        for (int k = 0; k < 8; ++k){
            const float f = bfu((unsigned short)v[k]);
            s[k] += f; q[k] += f*f;
        }
    }
    #pragma unroll
    for (int k = 0; k < 8; ++k){
        atomicAdd(&ss[c0+k], s[k]);
        atomicAdd(&sq[c0+k], q[k]);
    }
    __syncthreads();
    if (tid < CC){
        s1p[blockIdx.x*512 + tid]       = ss[tid];
        s1p[blockIdx.x*512 + 256 + tid] = sq[tid];
    }
    __syncthreads();
    if (tid == 0){
        __threadfence();                               // release partials
        const int old = atomicAdd(ticket, 1);
        isLast = (old == (int)gridDim.x - 1) ? 1 : 0;
    }
    __syncthreads();
    if (isLast){                                       // block-uniform
        __threadfence();                               // acquire partials
        const int a = tid >> 8;                        // 0 = sum, 1 = sumsq
        const int c = tid & 255;
        float acc = 0.f;
        #pragma unroll 8
        for (int bi = 0; bi < 192; ++bi)
            acc += __hip_atomic_load(&s1p[bi*512 + a*256 + c],
                                     __ATOMIC_RELAXED, __HIP_MEMORY_SCOPE_AGENT);
        if (a == 0) ss[c] = acc; else sq[c] = acc;
        __syncthreads();
        if (tid < CC){
            const float mean = ss[tid]/(float)RR;
            const float var  = sq[tid]/(float)RR - mean*mean;
            const float av = ld<T>(g1, tid) * rsqrtf(var + 1e-5f);
            ab1[tid] = av;
            ab1[CC + tid] = ld<T>(b1, tid) - mean*av;
        }
    }
}
__global__ __launch_bounds__(512) void k_st1(
        const bf16* __restrict__ xdf, float* __restrict__ s1p,
        int* __restrict__ ticket, const void* g1, const void* b1,
        const float* __restrict__ flag, float* __restrict__ ab1){
    if (flag[0] != 0.0f) st1_body<bf16>(xdf, s1p, ticket, g1, b1, ab1);
    else                 st1_body<float>(xdf, s1p, ticket, g1, b1, ab1);
}

// K7: wTf layout transform + bias2 via block LDS reduce (no atomics).
// Blocks 0..31 also zero st2p (8192 words) for k_gemm's atomic partials.
template<typename T>
__device__ void wt_body(const void* cw, const float* __restrict__ ab1,
                        bf16* __restrict__ wTf, float* __restrict__ bias2,
                        float* __restrict__ st2p){
    __shared__ float red[256];
    const int o = blockIdx.x;
    const int c = threadIdx.x;
    if (o < 32) st2p[o*256 + c] = 0.f;
    const float w = ld<T>(cw, (long long)o*CC + c);
    wTf[(((long long)(o >> 4)*32 + (c >> 3))*16 + (o & 15))*8 + (c & 7)] =
        __float2bfloat16(w * ab1[c]);
    red[c] = w * ab1[CC + c];
    __syncthreads();
    for (int d = 128; d > 0; d >>= 1){
        if (c < d) red[c] += red[c + d];
        __syncthreads();
    }
    if (c == 0) bias2[o] = red[0];
}
__global__ __launch_bounds__(256) void k_wt(
        const void* cw, const float* __restrict__ ab1,
        const float* __restrict__ flag, bf16* __restrict__ wTf,
        float* __restrict__ bias2, float* __restrict__ st2p){
    if (flag[0] != 0.0f) wt_body<bf16>(cw, ab1, wTf, bias2, st2p);
    else                 wt_body<float>(cw, ab1, wTf, bias2, st2p);
}

// K8: MFMA GEMM (unchanged). BN2 stats into 8-way atomic partials.
__global__ __launch_bounds__(256) void k_gemm(
        const bf16* __restrict__ xdf, const bf16* __restrict__ wTf,
        const float* __restrict__ bias2, const float* __restrict__ flag,
        void* __restrict__ y, float* __restrict__ st2p){
    __shared__ float ss[128], sq[128];
    const int tid = threadIdx.x;
    if (tid < 128){ ss[tid] = 0.f; sq[tid] = 0.f; }
    __syncthreads();
    const int wave = tid >> 6;
    const int lane = tid & 63;
    const int l16 = lane & 15;
    const int lq  = lane >> 4;
    const int mb = blockIdx.x;              // 0..383 (384 NOT pow2 — no masking)
    const int nb = blockIdx.y;              // 0..3
    const int mt = mb*4 + wave;
    const int n0t = nb*8;
    const short* ap = (const short*)xdf + ((long long)mt*32 + lq)*128 + (long long)l16*8;
    const short* bp = (const short*)wTf + ((long long)n0t*32 + lq)*128 + (long long)l16*8;
    f32x4 acc[8];
    #pragma unroll
    for (int nt = 0; nt < 8; ++nt) acc[nt] = (f32x4){0.f,0.f,0.f,0.f};
    #pragma unroll
    for (int kg0 = 0; kg0 < 8; ++kg0){
        const bf16x8 af = *((const bf16x8*)(ap + kg0*512));
        #pragma unroll
        for (int nt = 0; nt < 8; ++nt){
            const bf16x8 bfr = *((const bf16x8*)(bp + (long long)nt*4096 + kg0*512));
            acc[nt] = __builtin_amdgcn_mfma_f32_16x16x32_bf16(af, bfr, acc[nt], 0, 0, 0);
        }
    }
    const int row0 = mt*16 + lq*4;
    const bool isbf = (flag[0] != 0.0f);
    #pragma unroll
    for (int nt = 0; nt < 8; ++nt){
        const int col = nb*128 + nt*16 + l16;
        const float bz = bias2[col];
        float s = 0.f, q = 0.f;
        float v[4];
        #pragma unroll
        for (int r = 0; r < 4; ++r){
            v[r] = acc[nt][r] + bz;
            s += v[r]; q += v[r]*v[r];
        }
        if (isbf){
            bf16* yo = (bf16*)y;
            #pragma unroll
            for (int r = 0; r < 4; ++r)
                yo[(long long)(row0 + r)*CCO + col] = __float2bfloat16(v[r]);
        } else {
            float* yo = (float*)y;
            #pragma unroll
            for (int r = 0; r < 4; ++r)
                yo[(long long)(row0 + r)*CCO + col] = v[r];
        }
        s += __shfl_xor(s, 16); s += __shfl_xor(s, 32);
        q += __shfl_xor(q, 16); q += __shfl_xor(q, 32);
        if (lq == 0){
            atomicAdd(&ss[nt*16 + l16], s);
            atomicAdd(&sq[nt*16 + l16], q);
        }
    }
    __syncthreads();
    if (tid < 128){
        const int slot = (mb & 7)*1024;
        atomicAdd(&st2p[slot + nb*128 + tid], ss[tid]);
        atomicAdd(&st2p[slot + 512 + nb*128 + tid], sq[tid]);
    }
}

// K9 (R10): out = relu(y*a2 + b2) with BN2 finalize fused. Each block computes
// ab2 for all 512 channels from the 8-way st2p partials into LDS (16 L2 loads
// + 2 rsqrt per thread), then grid-strides over the output. 2048 blocks.
template<typename T>
__device__ void out_body(void* __restrict__ y, const float* __restrict__ st2p,
                         const void* g2, const void* b2, const bool isbf){
    __shared__ float a2[CCO], bb2[CCO];
    const int tid = threadIdx.x;
    for (int o = tid; o < CCO; o += 256){
        float s = 0.f, q = 0.f;
        #pragma unroll
        for (int p = 0; p < 8; ++p){
            s += st2p[p*1024 + o];
            q += st2p[p*1024 + 512 + o];
        }
        const float mean = s/(float)RR;
        const float var  = q/(float)RR - mean*mean;
        const float a = ld<T>(g2, o) * rsqrtf(var + 1e-5f);
        a2[o] = a;
        bb2[o] = ld<T>(b2, o) - mean*a;
    }
    __syncthreads();
    const long long tot = (long long)RR*CCO;           // 12582912
    const long long step = (long long)gridDim.x*256*4;
    for (long long i0 = ((long long)blockIdx.x*256 + tid)*4; i0 < tot; i0 += step){
        const int o0 = (int)(i0 & (CCO-1));
        if (isbf){
            unsigned short* p = (unsigned short*)y;
            ushort4 u = *(ushort4*)(p + i0);
            float v0 = bfu(u.x)*a2[o0  ] + bb2[o0  ];
            float v1 = bfu(u.y)*a2[o0+1] + bb2[o0+1];
            float v2 = bfu(u.z)*a2[o0+2] + bb2[o0+2];
            float v3 = bfu(u.w)*a2[o0+3] + bb2[o0+3];
            u.x = ubf(fmaxf(v0,0.f)); u.y = ubf(fmaxf(v1,0.f));
            u.z = ubf(fmaxf(v2,0.f)); u.w = ubf(fmaxf(v3,0.f));
            *(ushort4*)(p + i0) = u;
        } else {
            float* p = (float*)y;
            float4 v = *(float4*)(p + i0);
            v.x = fmaxf(v.x*a2[o0  ] + bb2[o0  ], 0.f);
            v.y = fmaxf(v.y*a2[o0+1] + bb2[o0+1], 0.f);
            v.z = fmaxf(v.z*a2[o0+2] + bb2[o0+2], 0.f);
            v.w = fmaxf(v.w*a2[o0+3] + bb2[o0+3], 0.f);
            *(float4*)(p + i0) = v;
        }
    }
}
__global__ __launch_bounds__(256) void k_out(
        void* __restrict__ y, const float* __restrict__ st2p,
        const void* g2, const void* b2, const float* __restrict__ flag){
    if (flag[0] != 0.0f) out_body<bf16>(y, st2p, g2, b2, true);
    else                 out_body<float>(y, st2p, g2, b2, false);
}

extern "C" void kernel_launch(void* const* d_in, const int* in_sizes, int n_in,
                              void* d_out, int out_size, void* d_ws, size_t ws_size,
                              hipStream_t stream){
    (void)in_sizes; (void)n_in; (void)out_size; (void)ws_size;
    const void* x   = d_in[0];
    const void* loc = d_in[1];
    const int*  ia  = (const int*)d_in[2];
    const int*  iat = (const int*)d_in[5];
    const void* wt  = d_in[6];
    const void* dww = d_in[9];
    const void* skw = d_in[10];
    const void* g1  = d_in[11];
    const void* b1  = d_in[12];
    const void* cw  = d_in[13];
    const void* g2  = d_in[14];
    const void* b2  = d_in[15];
    float* ws = (float*)d_ws;
    float* flag = ws + O_FLAG;
    int*  off  = (int*)(ws + O_OFF);
    int*  raw  = (int*)(ws + O_RAW);
    int*  list = (int*)(ws + O_LIST);
    int4* list4 = (int4*)(ws + O_L4);
    int*  tickets = (int*)(ws + O_TK);
    bf16* conv = (bf16*)(ws + O_CONV);
    bf16* xdf  = (bf16*)(ws + O_XD);
    bf16* wTf  = (bf16*)(ws + O_WT);

    // 10 dispatches total.
    k_init<<<dim3(SCN/256), dim3(256), 0, stream>>>(
        (const float*)loc, raw, tickets, flag);

    k_meta<<<dim3(NTOK/256), dim3(256), 0, stream>>>(loc, iat, flag, raw);

    k_scan<<<dim3(SCB), dim3(1024), 0, stream>>>(raw, off);

    k_fill<<<dim3(NTOK/256), dim3(256), 0, stream>>>(
        loc, ia, iat, wt, flag, off, list, list4);

    k_conv<<<dim3(BB*HW2), dim3(192), 0, stream>>>(x, dww, flag, off, list, conv);

    k_num<<<dim3(RR/4), dim3(256), 0, stream>>>(
        x, conv, skw, off, list4, flag, xdf);

    k_st1<<<dim3(192), dim3(512), 0, stream>>>(
        xdf, ws + O_S1P, &tickets[1], g1, b1, flag, ws + O_AB1);

    k_wt<<<dim3(CCO), dim3(256), 0, stream>>>(
        cw, ws + O_AB1, flag, wTf, ws + O_B2, ws + O_ST2P);

    k_gemm<<<dim3(384, 4), dim3(256), 0, stream>>>(
        xdf, wTf, ws + O_B2, flag, d_out, ws + O_ST2P);

    k_out<<<dim3(2048), dim3(256), 0, stream>>>(
        d_out, ws + O_ST2P, g2, b2, flag);
}

// Round 11
// 346.829 us; speedup vs baseline: 1.0418x; 1.0418x over previous
//
#include <hip/hip_runtime.h>
#include <hip/hip_bf16.h>

using bf16 = __hip_bfloat16;
typedef __attribute__((ext_vector_type(8))) short bf16x8;
typedef __attribute__((ext_vector_type(4))) float f32x4;

#define BB   8
#define NN   12288
#define NTOK (BB*NN)      // 98304
#define NTK  3072
#define CC   256
#define CCO  512
#define HH   128
#define WWI  96
#define HWIN (HH*WWI)     // 12288
#define H2   64
#define W2   48
#define HW2  (H2*W2)      // 3072
#define RR   (BB*NTK)     // 24576

// ---- workspace layout (float-word offsets)
#define O_CONV  0LL          // conv bf16: 6291456 elems -> 3145728 words
#define O_XD    6291456LL    // xdf bf16 fragment layout: 3145728 words
#define O_AUX   9437184LL    // 128 ints (scan block totals)
#define O_ST2P  9437440LL    // 8192 words: 8 partials x (512 sum | 512 sumsq)
#define O_WT    12582912LL   // wTf bf16 fragment layout: 65536 words
#define O_TK    12713984LL   // tickets: [0]=unused, [1]=st1
#define O_AB1   12715520LL   // 512
#define O_B2    12716032LL   // 512
#define O_AB2   12716544LL   // 1024
#define O_FLAG  12717568LL   // 4
#define O_S1P   12717572LL   // st1 partials: 192 blocks x 512 = 98304 words
#define O_OFF   12914180LL   // 122880 ints: joint [cells(98304) | targets(24576)]
#define O_LIST  13037060LL   // 196608 ints: listA (cells)
#define O_L4    13233668LL   // 786432 words: int4 per joint-list slot (targets)
// end 14020100 words = 56.1 MB (ws ~384 MB)

__device__ __forceinline__ float cvt(float v){ return v; }
__device__ __forceinline__ float cvt(bf16 v){ return __bfloat162float(v); }
template<typename T>
__device__ __forceinline__ float ld(const void* p, long long i){
    return cvt(((const T*)p)[i]);
}
__device__ __forceinline__ float bfu(unsigned short u){
    return __uint_as_float((unsigned)u << 16);
}
__device__ __forceinline__ unsigned short ubf(float f){
    bf16 h = __float2bfloat16(f);
    return *(unsigned short*)&h;
}
template<typename T>
__device__ __forceinline__ f32x4 ld4(const void* p, long long i);
template<>
__device__ __forceinline__ f32x4 ld4<bf16>(const void* p, long long i){
    const ushort4 u = *(const ushort4*)((const unsigned short*)p + i);
    return (f32x4){bfu(u.x), bfu(u.y), bfu(u.z), bfu(u.w)};
}
template<>
__device__ __forceinline__ f32x4 ld4<float>(const void* p, long long i){
    const float4 v = *(const float4*)((const float*)p + i);
    return (f32x4){v.x, v.y, v.z, v.w};
}

#define SCN  (NTOK + RR)     // 122880 = 480*256 = 120*1024
#define SCB  120             // scan tiles of 1024

// K0: one init kernel replaces 3 memsets + k_flag. Zeroes off[SCN]; block 0
// zeroes tickets and computes the dtype flag (loc ~ U(-1,1) in f32;
// bf16-reinterp values are huge).
__global__ __launch_bounds__(256) void k_init(
        const float* __restrict__ locf, int* __restrict__ off,
        int* __restrict__ tickets, float* __restrict__ flag){
    const int gid = blockIdx.x*256 + threadIdx.x;
    off[gid] = 0;
    if (blockIdx.x == 0){
        if (threadIdx.x < 2) tickets[threadIdx.x] = 0;
        if (threadIdx.x == 0){
            int bad = 0;
            for (int i = 0; i < 64; ++i){
                const float v = locf[i];
                if (!(v >= -1.0f && v <= 1.0f)) bad = 1;
            }
            flag[0] = bad ? 1.0f : 0.0f;
        }
    }
}

__device__ __forceinline__ int2 gidx2(float lx, float ly, int h, int w){
    lx = fminf(fmaxf(lx, -1.f), 1.f);
    ly = fminf(fmaxf(ly, -1.f), 1.f);
    int xi = (int)rintf(0.5f*(lx+1.f)*(float)w - 0.5f);
    int yi = (int)rintf(0.5f*(ly+1.f)*(float)h - 0.5f);
    xi = min(max(xi,0), w-1); yi = min(max(yi,0), h-1);
    return make_int2(xi, yi);
}

// K1: joint histogram (cells then targets).
template<typename T>
__device__ void meta_body(const void* loc, const int* __restrict__ iat,
                          int* __restrict__ off){
    const int tok = blockIdx.x*256 + threadIdx.x;
    const int b = tok / NN;
    const float lx = ld<T>(loc, 2LL*tok);
    const float ly = ld<T>(loc, 2LL*tok + 1);
    const int2 g1 = gidx2(lx, ly, HH, WWI);
    atomicAdd(&off[b*HWIN + g1.x + g1.y*WWI], 1);
    atomicAdd(&off[NTOK + b*NTK + iat[tok]], 1);
}
__global__ __launch_bounds__(256) void k_meta(
        const void* loc, const int* __restrict__ iat,
        const float* __restrict__ flag, int* __restrict__ off){
    if (flag[0] != 0.0f) meta_body<bf16>(loc, iat, off);
    else                 meta_body<float>(loc, iat, off);
}

// K2a: per-tile exclusive scan + tile totals (no cross-block waiting).
__global__ __launch_bounds__(1024) void k_scan1(int* __restrict__ off, int* __restrict__ aux){
    __shared__ int sm[1024];
    const int tid = threadIdx.x;
    const int gid = blockIdx.x*1024 + tid;
    const int v = off[gid];
    sm[tid] = v;
    __syncthreads();
    for (int d = 1; d < 1024; d <<= 1){
        const int t = (tid >= d) ? sm[tid-d] : 0;
        __syncthreads();
        sm[tid] += t;
        __syncthreads();
    }
    off[gid] = sm[tid] - v;                    // exclusive within tile
    if (tid == 1023) aux[blockIdx.x] = sm[1023];
}
// K2b: add tile prefix; each block redundantly sums aux[0..b-1] from LDS
// (<=119 adds, hang-proof).
__global__ __launch_bounds__(1024) void k_scan3(int* __restrict__ off, const int* __restrict__ aux){
    __shared__ int sm[SCB];
    __shared__ int sRun;
    const int tid = threadIdx.x;
    if (tid < SCB) sm[tid] = aux[tid];
    __syncthreads();
    if (tid == 0){
        int r = 0;
        for (int j = 0; j < (int)blockIdx.x; ++j) r += sm[j];
        sRun = r;
    }
    __syncthreads();
    off[blockIdx.x*1024 + tid] += sRun;
}

// K3: fill joint CSR. listA[pa] = x-row; list4[pb] = {rx, rc, wv_bits, 0}.
template<typename T>
__device__ void fill_body(const void* loc, const int* __restrict__ ia,
                          const int* __restrict__ iat, const void* wt,
                          int* __restrict__ off, int* __restrict__ list,
                          int4* __restrict__ list4){
    const int tok = blockIdx.x*256 + threadIdx.x;
    const int b = tok / NN;
    const float lx = ld<T>(loc, 2LL*tok);
    const float ly = ld<T>(loc, 2LL*tok + 1);
    const int2 g1 = gidx2(lx, ly, HH, WWI);
    const int2 g2 = gidx2(lx, ly, H2, W2);
    const float wv = ld<T>(wt, tok);
    const int rx = b*NN + ia[tok];
    const int pa = atomicAdd(&off[b*HWIN + g1.x + g1.y*WWI], 1);
    list[pa] = rx;
    const int pb = atomicAdd(&off[NTOK + b*NTK + iat[tok]], 1);
    int4 e; e.x = rx; e.y = b*HW2 + g2.x + g2.y*W2; e.z = __float_as_int(wv); e.w = 0;
    list4[pb] = e;
}
__global__ __launch_bounds__(256) void k_fill(
        const void* loc, const int* __restrict__ ia, const int* __restrict__ iat,
        const void* wt, const float* __restrict__ flag,
        int* __restrict__ off, int* __restrict__ list, int4* __restrict__ list4){
    if (flag[0] != 0.0f) fill_body<bf16>(loc, ia, iat, wt, off, list, list4);
    else                 fill_body<float>(loc, ia, iat, wt, off, list, list4);
}

// K4: gather-conv (R4's measured-best form, unchanged).
template<typename T>
__device__ void conv_body(const void* x, const void* dww,
                          const int* __restrict__ off, const int* __restrict__ list,
                          bf16* __restrict__ conv){
    __shared__ f32x4 red[3][64];
    const int tid = threadIdx.x;
    const int kh = tid >> 6;
    const int lane = tid & 63;
    const int ch0 = lane*4;
    const int cell = blockIdx.x;
    const int b = cell / HW2;
    const int p = cell % HW2;
    const int oh = p / W2, ow = p % W2;
    const int ih = 2*oh - 1 + kh;
    f32x4 part = (f32x4){0.f,0.f,0.f,0.f};
    if (ih >= 0){
        const int gbase = b*HWIN + ih*WWI + 2*ow - 1;
        const int e0 = (gbase >= 0) ? off[gbase] : 0;
        const int e1 = off[gbase+1];
        const int e2 = off[gbase+2];
        const int ms = (ow > 0) ? off[gbase-1] : e0;
        f32x4 w0, w1, w2;
        #pragma unroll
        for (int c = 0; c < 4; ++c){
            w0[c] = ld<T>(dww, (long long)(ch0+c)*9 + kh*3 + 0);
            w1[c] = ld<T>(dww, (long long)(ch0+c)*9 + kh*3 + 1);
            w2[c] = ld<T>(dww, (long long)(ch0+c)*9 + kh*3 + 2);
        }
        f32x4 b0 = (f32x4){0.f,0.f,0.f,0.f};
        f32x4 b1 = (f32x4){0.f,0.f,0.f,0.f};
        f32x4 b2 = (f32x4){0.f,0.f,0.f,0.f};
        int idx = ms;
        while (idx < e2){
            const int cnt = min(e2 - idx, 64);
            const int tokv = (lane < cnt) ? list[idx + lane] : 0;
            int j = 0;
            for (; j + 4 <= cnt; j += 4){
                int oxs[4];
                #pragma unroll
                for (int u = 0; u < 4; ++u)
                    oxs[u] = __shfl(tokv, j+u)*CC + ch0;
                f32x4 xv[4];
                #pragma unroll
                for (int u = 0; u < 4; ++u) xv[u] = ld4<T>(x, (long long)oxs[u]);
                #pragma unroll
                for (int u = 0; u < 4; ++u){
                    const int gi = idx + j + u;
                    if (gi < e0)      b0 += xv[u];
                    else if (gi < e1) b1 += xv[u];
                    else              b2 += xv[u];
                }
            }
            for (; j < cnt; ++j){
                const f32x4 xv = ld4<T>(x, (long long)(__shfl(tokv, j)*CC + ch0));
                const int gi = idx + j;
                if (gi < e0)      b0 += xv;
                else if (gi < e1) b1 += xv;
                else              b2 += xv;
            }
            idx += cnt;
        }
        const float r0 = 1.0f/((float)(e0 - ms) + 1e-6f);
        const float r1 = 1.0f/((float)(e1 - e0) + 1e-6f);
        const float r2 = 1.0f/((float)(e2 - e1) + 1e-6f);
        #pragma unroll
        for (int c = 0; c < 4; ++c)
            part[c] = w0[c]*b0[c]*r0 + w1[c]*b1[c]*r1 + w2[c]*b2[c]*r2;
    }
    red[kh][lane] = part;
    __syncthreads();
    if (kh == 0){
        const f32x4 t0 = red[0][lane];
        const f32x4 t1 = red[1][lane];
        const f32x4 t2 = red[2][lane];
        ushort4 o;
        o.x = ubf(t0[0]+t1[0]+t2[0]);
        o.y = ubf(t0[1]+t1[1]+t2[1]);
        o.z = ubf(t0[2]+t1[2]+t2[2]);
        o.w = ubf(t0[3]+t1[3]+t2[3]);
        *(ushort4*)((unsigned short*)conv + (long long)cell*CC + ch0) = o;
    }
}
__global__ __launch_bounds__(192) void k_conv(
        const void* x, const void* dww, const float* __restrict__ flag,
        const int* __restrict__ off, const int* __restrict__ list,
        bf16* __restrict__ conv){
    if (flag[0] != 0.0f) conv_body<bf16>(x, dww, off, list, conv);
    else                 conv_body<float>(x, dww, off, list, conv);
}

// K5: one target per wave; chain off -> list4 -> x/conv; 8-wide static prefetch.
#define PFN 8
template<typename T>
__device__ void num_body(const void* x, const bf16* __restrict__ conv,
                         const void* skw,
                         const int* __restrict__ off, const int4* __restrict__ list4,
                         bf16* __restrict__ xdf){
    const int tid = threadIdx.x;
    const int wave = tid >> 6;
    const int lane = tid & 63;
    const int ch0 = lane*4;
    const f32x4 sk = ld4<T>(skw, ch0);
    const int gt = blockIdx.x*4 + wave;
    const int gj = NTOK + gt;
    int offv = 0;
    if (lane < 2) offv = off[gj - 1 + lane];
    const int s = __shfl(offv, 0);
    const int e = __shfl(offv, 1);
    f32x4 a = (f32x4){0.f,0.f,0.f,0.f};
    float den = 0.f;
    int idx = s;
    while (idx < e){
        int4 t[PFN];
        #pragma unroll
        for (int k = 0; k < PFN; ++k)
            if (idx + k < e) t[k] = list4[idx + k];
        #pragma unroll
        for (int k = 0; k < PFN; ++k){
            if (idx + k < e){
                const float wv = __int_as_float(t[k].z);
                const f32x4 xv = ld4<T>(x, (long long)t[k].x*CC + ch0);
                const f32x4 cv = ld4<bf16>(conv, (long long)t[k].y*CC + ch0);
                #pragma unroll
                for (int c = 0; c < 4; ++c)
                    a[c] += wv*(sk[c]*xv[c] + cv[c]);
                den += wv;
            }
        }
        idx += PFN;
    }
    const float rl = 1.0f/(den + 1e-6f);
    ushort4 o;
    o.x = ubf(a[0]*rl); o.y = ubf(a[1]*rl);
    o.z = ubf(a[2]*rl); o.w = ubf(a[3]*rl);
    const long long bi = (long long)(gt >> 4)*4096 + (long long)(ch0 >> 3)*128
                       + (long long)(gt & 15)*8 + (ch0 & 7);
    *(ushort4*)((unsigned short*)xdf + bi) = o;
}
__global__ __launch_bounds__(256) void k_num(
        const void* x, const bf16* __restrict__ conv, const void* skw,
        const int* __restrict__ off, const int4* __restrict__ list4,
        const float* __restrict__ flag,
        bf16* __restrict__ xdf){
    if (flag[0] != 0.0f) num_body<bf16>(x, conv, skw, off, list4, xdf);
    else                 num_body<float>(x, conv, skw, off, list4, xdf);
}

// K6: BN1 stats from xdf + fused finalize via last-block ticket (R9 parallel
// coalesced finalize, __hip_atomic_load RELAXED/AGENT).
template<typename T>
__device__ void st1_body(const bf16* __restrict__ xdf, float* __restrict__ s1p,
                         int* __restrict__ ticket, const void* g1, const void* b1,
                         float* __restrict__ ab1){
    __shared__ float ss[CC], sq[CC];
    __shared__ int isLast;
    const int tid = threadIdx.x;
    if (tid < CC){ ss[tid] = 0.f; sq[tid] = 0.f; }
    __syncthreads();
    const int tl = tid & 15;
    const int cg = tid >> 4;          // 0..31 channel group
    const int c0 = cg*8;
    float s[8], q[8];
    #pragma unroll
    for (int k = 0; k < 8; ++k){ s[k] = 0.f; q[k] = 0.f; }
    for (int sb = blockIdx.x; sb < RR/16; sb += gridDim.x){
        const long long o = (long long)sb*512 + cg*16 + tl;
        const bf16x8 v = *((const bf16x8*)xdf + o);
        #pragma unroll
        for (int k = 0; k < 8; ++k){
            const float f = bfu((unsigned short)v[k]);
            s[k] += f; q[k] += f*f;
        }
    }
    #pragma unroll
    for (int k = 0; k < 8; ++k){
        atomicAdd(&ss[c0+k], s[k]);
        atomicAdd(&sq[c0+k], q[k]);
    }
    __syncthreads();
    if (tid < CC){
        s1p[blockIdx.x*512 + tid]       = ss[tid];
        s1p[blockIdx.x*512 + 256 + tid] = sq[tid];
    }
    __syncthreads();
    if (tid == 0){
        __threadfence();                               // release partials
        const int old = atomicAdd(ticket, 1);
        isLast = (old == (int)gridDim.x - 1) ? 1 : 0;
    }
    __syncthreads();
    if (isLast){                                       // block-uniform
        __threadfence();                               // acquire partials
        const int a = tid >> 8;                        // 0 = sum, 1 = sumsq
        const int c = tid & 255;
        float acc = 0.f;
        #pragma unroll 8
        for (int bi = 0; bi < 192; ++bi)
            acc += __hip_atomic_load(&s1p[bi*512 + a*256 + c],
                                     __ATOMIC_RELAXED, __HIP_MEMORY_SCOPE_AGENT);
        if (a == 0) ss[c] = acc; else sq[c] = acc;
        __syncthreads();
        if (tid < CC){
            const float mean = ss[tid]/(float)RR;
            const float var  = sq[tid]/(float)RR - mean*mean;
            const float av = ld<T>(g1, tid) * rsqrtf(var + 1e-5f);
            ab1[tid] = av;
            ab1[CC + tid] = ld<T>(b1, tid) - mean*av;
        }
    }
}
__global__ __launch_bounds__(512) void k_st1(
        const bf16* __restrict__ xdf, float* __restrict__ s1p,
        int* __restrict__ ticket, const void* g1, const void* b1,
        const float* __restrict__ flag, float* __restrict__ ab1){
    if (flag[0] != 0.0f) st1_body<bf16>(xdf, s1p, ticket, g1, b1, ab1);
    else                 st1_body<float>(xdf, s1p, ticket, g1, b1, ab1);
}

// K7: wTf layout transform + bias2 via block LDS reduce (no atomics).
// Blocks 0..31 also zero st2p (8192 words) for k_gemm's atomic partials.
template<typename T>
__device__ void wt_body(const void* cw, const float* __restrict__ ab1,
                        bf16* __restrict__ wTf, float* __restrict__ bias2,
                        float* __restrict__ st2p){
    __shared__ float red[256];
    const int o = blockIdx.x;
    const int c = threadIdx.x;
    if (o < 32) st2p[o*256 + c] = 0.f;
    const float w = ld<T>(cw, (long long)o*CC + c);
    wTf[(((long long)(o >> 4)*32 + (c >> 3))*16 + (o & 15))*8 + (c & 7)] =
        __float2bfloat16(w * ab1[c]);
    red[c] = w * ab1[CC + c];
    __syncthreads();
    for (int d = 128; d > 0; d >>= 1){
        if (c < d) red[c] += red[c + d];
        __syncthreads();
    }
    if (c == 0) bias2[o] = red[0];
}
__global__ __launch_bounds__(256) void k_wt(
        const void* cw, const float* __restrict__ ab1,
        const float* __restrict__ flag, bf16* __restrict__ wTf,
        float* __restrict__ bias2, float* __restrict__ st2p){
    if (flag[0] != 0.0f) wt_body<bf16>(cw, ab1, wTf, bias2, st2p);
    else                 wt_body<float>(cw, ab1, wTf, bias2, st2p);
}

// K8: MFMA GEMM (unchanged). BN2 stats into 8-way atomic partials.
__global__ __launch_bounds__(256) void k_gemm(
        const bf16* __restrict__ xdf, const bf16* __restrict__ wTf,
        const float* __restrict__ bias2, const float* __restrict__ flag,
        void* __restrict__ y, float* __restrict__ st2p){
    __shared__ float ss[128], sq[128];
    const int tid = threadIdx.x;
    if (tid < 128){ ss[tid] = 0.f; sq[tid] = 0.f; }
    __syncthreads();
    const int wave = tid >> 6;
    const int lane = tid & 63;
    const int l16 = lane & 15;
    const int lq  = lane >> 4;
    const int mb = blockIdx.x;              // 0..383 (384 NOT pow2 — no masking)
    const int nb = blockIdx.y;              // 0..3
    const int mt = mb*4 + wave;
    const int n0t = nb*8;
    const short* ap = (const short*)xdf + ((long long)mt*32 + lq)*128 + (long long)l16*8;
    const short* bp = (const short*)wTf + ((long long)n0t*32 + lq)*128 + (long long)l16*8;
    f32x4 acc[8];
    #pragma unroll
    for (int nt = 0; nt < 8; ++nt) acc[nt] = (f32x4){0.f,0.f,0.f,0.f};
    #pragma unroll
    for (int kg0 = 0; kg0 < 8; ++kg0){
        const bf16x8 af = *((const bf16x8*)(ap + kg0*512));
        #pragma unroll
        for (int nt = 0; nt < 8; ++nt){
            const bf16x8 bfr = *((const bf16x8*)(bp + (long long)nt*4096 + kg0*512));
            acc[nt] = __builtin_amdgcn_mfma_f32_16x16x32_bf16(af, bfr, acc[nt], 0, 0, 0);
        }
    }
    const int row0 = mt*16 + lq*4;
    const bool isbf = (flag[0] != 0.0f);
    #pragma unroll
    for (int nt = 0; nt < 8; ++nt){
        const int col = nb*128 + nt*16 + l16;
        const float bz = bias2[col];
        float s = 0.f, q = 0.f;
        float v[4];
        #pragma unroll
        for (int r = 0; r < 4; ++r){
            v[r] = acc[nt][r] + bz;
            s += v[r]; q += v[r]*v[r];
        }
        if (isbf){
            bf16* yo = (bf16*)y;
            #pragma unroll
            for (int r = 0; r < 4; ++r)
                yo[(long long)(row0 + r)*CCO + col] = __float2bfloat16(v[r]);
        } else {
            float* yo = (float*)y;
            #pragma unroll
            for (int r = 0; r < 4; ++r)
                yo[(long long)(row0 + r)*CCO + col] = v[r];
        }
        s += __shfl_xor(s, 16); s += __shfl_xor(s, 32);
        q += __shfl_xor(q, 16); q += __shfl_xor(q, 32);
        if (lq == 0){
            atomicAdd(&ss[nt*16 + l16], s);
            atomicAdd(&sq[nt*16 + l16], q);
        }
    }
    __syncthreads();
    if (tid < 128){
        const int slot = (mb & 7)*1024;
        atomicAdd(&st2p[slot + nb*128 + tid], ss[tid]);
        atomicAdd(&st2p[slot + 512 + nb*128 + tid], sq[tid]);
    }
}

// K9: finalize BN2 scale/shift from 8 partials.
template<typename T>
__device__ void bn2_body(const float* __restrict__ st2p, const void* g2, const void* b2,
                         float* __restrict__ ab2){
    const int tid = threadIdx.x;
    float s = 0.f, q = 0.f;
    #pragma unroll
    for (int p = 0; p < 8; ++p){
        s += st2p[p*1024 + tid];
        q += st2p[p*1024 + 512 + tid];
    }
    const float mean = s/(float)RR;
    const float var  = q/(float)RR - mean*mean;
    const float a = ld<T>(g2, tid) * rsqrtf(var + 1e-5f);
    ab2[tid] = a;
    ab2[CCO + tid] = ld<T>(b2, tid) - mean*a;
}
__global__ __launch_bounds__(512) void k_bn2(
        const float* __restrict__ st2p, const void* g2, const void* b2,
        const float* __restrict__ flag, float* __restrict__ ab2){
    if (flag[0] != 0.0f) bn2_body<bf16>(st2p, g2, b2, ab2);
    else                 bn2_body<float>(st2p, g2, b2, ab2);
}

// K10: in-place on d_out: out = relu(y*a2 + b2), 4 elems/thread.
__global__ __launch_bounds__(256) void k_out(
        void* __restrict__ y, const float* __restrict__ ab2,
        const float* __restrict__ flag){
    const long long i0 = ((long long)blockIdx.x*256 + threadIdx.x)*4;
    const int o0 = (int)(i0 & (CCO-1));
    if (flag[0] != 0.0f){
        unsigned short* p = (unsigned short*)y;
        ushort4 u = *(ushort4*)(p + i0);
        float v0 = bfu(u.x)*ab2[o0  ] + ab2[CCO + o0  ];
        float v1 = bfu(u.y)*ab2[o0+1] + ab2[CCO + o0+1];
        float v2 = bfu(u.z)*ab2[o0+2] + ab2[CCO + o0+2];
        float v3 = bfu(u.w)*ab2[o0+3] + ab2[CCO + o0+3];
        u.x = ubf(fmaxf(v0,0.f)); u.y = ubf(fmaxf(v1,0.f));
        u.z = ubf(fmaxf(v2,0.f)); u.w = ubf(fmaxf(v3,0.f));
        *(ushort4*)(p + i0) = u;
    } else {
        float* p = (float*)y;
        float4 v = *(float4*)(p + i0);
        v.x = fmaxf(v.x*ab2[o0  ] + ab2[CCO + o0  ], 0.f);
        v.y = fmaxf(v.y*ab2[o0+1] + ab2[CCO + o0+1], 0.f);
        v.z = fmaxf(v.z*ab2[o0+2] + ab2[CCO + o0+2], 0.f);
        v.w = fmaxf(v.w*ab2[o0+3] + ab2[CCO + o0+3], 0.f);
        *(float4*)(p + i0) = v;
    }
}

extern "C" void kernel_launch(void* const* d_in, const int* in_sizes, int n_in,
                              void* d_out, int out_size, void* d_ws, size_t ws_size,
                              hipStream_t stream){
    (void)in_sizes; (void)n_in; (void)out_size; (void)ws_size;
    const void* x   = d_in[0];
    const void* loc = d_in[1];
    const int*  ia  = (const int*)d_in[2];
    const int*  iat = (const int*)d_in[5];
    const void* wt  = d_in[6];
    const void* dww = d_in[9];
    const void* skw = d_in[10];
    const void* g1  = d_in[11];
    const void* b1  = d_in[12];
    const void* cw  = d_in[13];
    const void* g2  = d_in[14];
    const void* b2  = d_in[15];
    float* ws = (float*)d_ws;
    float* flag = ws + O_FLAG;
    int*  off  = (int*)(ws + O_OFF);
    int*  list = (int*)(ws + O_LIST);
    int4* list4 = (int4*)(ws + O_L4);
    int*  aux  = (int*)(ws + O_AUX);
    int*  tickets = (int*)(ws + O_TK);
    bf16* conv = (bf16*)(ws + O_CONV);
    bf16* xdf  = (bf16*)(ws + O_XD);
    bf16* wTf  = (bf16*)(ws + O_WT);

    // 12 dispatches total, no memsets.
    k_init<<<dim3(SCN/256), dim3(256), 0, stream>>>(
        (const float*)loc, off, tickets, flag);

    k_meta<<<dim3(NTOK/256), dim3(256), 0, stream>>>(loc, iat, flag, off);

    k_scan1<<<dim3(SCB), dim3(1024), 0, stream>>>(off, aux);
    k_scan3<<<dim3(SCB), dim3(1024), 0, stream>>>(off, aux);

    k_fill<<<dim3(NTOK/256), dim3(256), 0, stream>>>(
        loc, ia, iat, wt, flag, off, list, list4);

    k_conv<<<dim3(BB*HW2), dim3(192), 0, stream>>>(x, dww, flag, off, list, conv);

    k_num<<<dim3(RR/4), dim3(256), 0, stream>>>(
        x, conv, skw, off, list4, flag, xdf);

    k_st1<<<dim3(192), dim3(512), 0, stream>>>(
        xdf, ws + O_S1P, &tickets[1], g1, b1, flag, ws + O_AB1);

    k_wt<<<dim3(CCO), dim3(256), 0, stream>>>(
        cw, ws + O_AB1, flag, wTf, ws + O_B2, ws + O_ST2P);

    k_gemm<<<dim3(384, 4), dim3(256), 0, stream>>>(
        xdf, wTf, ws + O_B2, flag, d_out, ws + O_ST2P);

    k_bn2<<<dim3(1), dim3(512), 0, stream>>>(ws + O_ST2P, g2, b2, flag, ws + O_AB2);

    k_out<<<dim3((RR*CCO)/1024, 1), dim3(256), 0, stream>>>(d_out, ws + O_AB2, flag);
}